// Round 2
// baseline (151.160 us; speedup 1.0000x reference)
//
#include <hip/hip_runtime.h>

// EmbeddingDropout: out[t,:] = weight[x[t],:] * mask[x[t]]
// B*S = 16384 tokens, D = 512 fp32 (128 float4 per row).
//
// Structure: ONE WAVE PER ROW. The token index is wave-uniform, so we
// readfirstlane it and let x/mask loads become scalar s_loads (1 per wave
// instead of 64 redundant VMEM loads). Each lane moves 2 float4s
// (lane, lane+64) -> 2 independent 16B loads in flight per thread.
// Nontemporal stores: output is write-once, keep it out of L2 so the
// gathered weight rows stay cached.
//
// Note: __builtin_nontemporal_store requires a native clang vector type,
// not HIP_vector_type<float,4> -> use ext_vector_type(4) float.

typedef float v4f __attribute__((ext_vector_type(4)));

__global__ __launch_bounds__(256) void EmbeddingDropout_70592082477707_kernel(
    const int* __restrict__ x,        // [B*S] token ids (int32)
    const v4f* __restrict__ w,        // [V, D/4] weight as float4
    const float* __restrict__ mask,   // [V] per-row dropout scale
    v4f* __restrict__ out,            // [B*S, D/4]
    int n_tokens)                     // B*S
{
    int wave = (blockIdx.x * blockDim.x + threadIdx.x) >> 6;  // global wave id
    int lane = threadIdx.x & 63;
    if (wave >= n_tokens) return;

    // Token index is wave-uniform: force it to SGPR so x/mask loads are scalar.
    int t   = __builtin_amdgcn_readfirstlane(wave);
    int row = __builtin_amdgcn_readfirstlane(x[t]);
    float m = mask[row];              // uniform row -> s_load

    const v4f* __restrict__ src = w   + (size_t)row * 128;
    v4f*       __restrict__ dst = out + (size_t)t   * 128;

    // Two independent 16B loads per lane (cols lane and lane+64).
    v4f v0 = src[lane];
    v4f v1 = src[lane + 64];

    v0 *= m;
    v1 *= m;

    __builtin_nontemporal_store(v0, &dst[lane]);
    __builtin_nontemporal_store(v1, &dst[lane + 64]);
}

extern "C" void kernel_launch(void* const* d_in, const int* in_sizes, int n_in,
                              void* d_out, int out_size, void* d_ws, size_t ws_size,
                              hipStream_t stream) {
    const int*   x    = (const int*)d_in[0];      // [B*S] int32
    const v4f*   w    = (const v4f*)d_in[1];      // [V, 512] fp32 -> float4
    const float* mask = (const float*)d_in[2];    // [V] fp32
    v4f*         out  = (v4f*)d_out;              // [B*S, 512] fp32 -> float4

    int n_tokens = out_size / 512;                // 8*2048 = 16384 rows
    int block = 256;                              // 4 waves = 4 rows per block
    int grid = (n_tokens + 3) / 4;                // 4096 blocks

    EmbeddingDropout_70592082477707_kernel<<<grid, block, 0, stream>>>(
        x, w, mask, out, n_tokens);
}